// Round 1
// baseline (397.023 us; speedup 1.0000x reference)
//
#include <hip/hip_runtime.h>
#include <hip/hip_bf16.h>

// ---------------------------------------------------------------------------
// TernaryDense: C[M,N] = A[M,K] (fp32) @ ternary(W[K,N]) (fp32)
// ternary(w) = sign(w) if 0.5 <= |w| < 1.5 else 0   (exact, fp32 compares)
//
// Strategy: exact ternarize + transpose W -> bf16 N x K in d_ws,
//           cast A -> bf16 M x K in d_ws,
//           bf16 MFMA GEMM (m97 structure: 128x128 tile, BK=32,
//           global_load_lds width 16, 2-barrier K loop).
// ---------------------------------------------------------------------------

#define LDSP(p) ((__attribute__((address_space(3))) void*)(p))
#define GLBP(p) ((const __attribute__((address_space(1))) void*)(p))

typedef __attribute__((ext_vector_type(8))) short bf16x8;
typedef __attribute__((ext_vector_type(4))) float f32x4;

static __device__ __forceinline__ unsigned short f2bf_rne(float f) {
    unsigned u = __float_as_uint(f);
    unsigned r = (u + 0x7FFFu + ((u >> 16) & 1u)) >> 16;
    return (unsigned short)r;
}

static __device__ __forceinline__ unsigned short tern_bf16(float v) {
    float a = fabsf(v);
    if (a >= 0.5f && a < 1.5f)
        return (v > 0.0f) ? (unsigned short)0x3F80u : (unsigned short)0xBF80u;
    return (unsigned short)0;
}

// --- pre-pass 1: A fp32 -> bf16, vectorized 8 elems/thread/iter -------------
__global__ __launch_bounds__(256) void cvtA_kernel(
    const float* __restrict__ in, unsigned short* __restrict__ out, long n8) {
    long i = (long)blockIdx.x * blockDim.x + threadIdx.x;
    long stride = (long)gridDim.x * blockDim.x;
    for (; i < n8; i += stride) {
        float4 v0 = *(const float4*)(in + i * 8);
        float4 v1 = *(const float4*)(in + i * 8 + 4);
        unsigned short o[8] = {f2bf_rne(v0.x), f2bf_rne(v0.y), f2bf_rne(v0.z), f2bf_rne(v0.w),
                               f2bf_rne(v1.x), f2bf_rne(v1.y), f2bf_rne(v1.z), f2bf_rne(v1.w)};
        *(int4*)(out + i * 8) = *(const int4*)o;
    }
}

// --- pre-pass 2: ternarize W[K,N] and transpose -> Wt[N,K] bf16 -------------
// 64x64 tiles via LDS; reads and writes both coalesced (16B/lane).
__global__ __launch_bounds__(256) void ternT_kernel(
    const float* __restrict__ W, unsigned short* __restrict__ Wt, int K, int N) {
    __shared__ unsigned short tile[64][72];  // +8 pad to break bank alias
    const int k0 = blockIdx.y * 64;
    const int n0 = blockIdx.x * 64;
    const int t = threadIdx.x;
#pragma unroll
    for (int i = 0; i < 4; ++i) {
        int e = i * 1024 + t * 4;       // element in 64x64 tile (row-major k,n)
        int r = e >> 6, c = e & 63;
        float4 v = *(const float4*)(W + (size_t)(k0 + r) * N + n0 + c);
        tile[r][c + 0] = tern_bf16(v.x);
        tile[r][c + 1] = tern_bf16(v.y);
        tile[r][c + 2] = tern_bf16(v.z);
        tile[r][c + 3] = tern_bf16(v.w);
    }
    __syncthreads();
#pragma unroll
    for (int i = 0; i < 2; ++i) {
        int e = i * 2048 + t * 8;       // element in 64x64 output tile (n,k)
        int n = e >> 6, kk = e & 63;
        unsigned short o[8];
#pragma unroll
        for (int j = 0; j < 8; ++j) o[j] = tile[kk + j][n];
        *(int4*)(Wt + (size_t)(n0 + n) * K + k0 + kk) = *(const int4*)o;
    }
}

// --- GEMM: C[M,N] = Abf[M,K] @ Bt[N,K]^T, bf16 MFMA 16x16x32 ----------------
#define BM 128
#define BN 128
#define BK 32

__global__ __launch_bounds__(256) void gemm_bf16_kernel(
    const unsigned short* __restrict__ A,   // M x K bf16
    const unsigned short* __restrict__ Bt,  // N x K bf16
    float* __restrict__ C, int M, int N, int K) {
    __shared__ alignas(16) unsigned short Al[BM * BK];
    __shared__ alignas(16) unsigned short Bl[BN * BK];

    const int t = threadIdx.x;
    const int lane = t & 63;
    const int wave = t >> 6;
    const int wr = wave >> 1, wc = wave & 1;   // 2x2 wave grid, each 64x64 out
    const int brow = blockIdx.y * BM;
    const int bcol = blockIdx.x * BN;
    const int l15 = lane & 15;
    const int kgrp = lane >> 4;                // 0..3

    f32x4 acc[4][4] = {};

    for (int k0 = 0; k0 < K; k0 += BK) {
        // stage A tile (128x32) and B tile (128x32): 2 + 2 global_load_lds x16B
#pragma unroll
        for (int i = 0; i < 2; ++i) {
            int e = i * 2048 + t * 8;
            int r = e >> 5, c = e & 31;
            const unsigned short* src = A + (size_t)(brow + r) * K + (k0 + c);
            unsigned short* dst = Al + i * 2048 + wave * 512;  // wave-uniform base
            __builtin_amdgcn_global_load_lds(GLBP(src), LDSP(dst), 16, 0, 0);
        }
#pragma unroll
        for (int i = 0; i < 2; ++i) {
            int e = i * 2048 + t * 8;
            int r = e >> 5, c = e & 31;
            const unsigned short* src = Bt + (size_t)(bcol + r) * K + (k0 + c);
            unsigned short* dst = Bl + i * 2048 + wave * 512;
            __builtin_amdgcn_global_load_lds(GLBP(src), LDSP(dst), 16, 0, 0);
        }
        __syncthreads();   // drains vmcnt(0) before barrier

        bf16x8 af[4], bfr[4];
#pragma unroll
        for (int mf = 0; mf < 4; ++mf)
            af[mf] = *(const bf16x8*)(Al + (wr * 64 + mf * 16 + l15) * BK + kgrp * 8);
#pragma unroll
        for (int nf = 0; nf < 4; ++nf)
            bfr[nf] = *(const bf16x8*)(Bl + (wc * 64 + nf * 16 + l15) * BK + kgrp * 8);

#pragma unroll
        for (int mf = 0; mf < 4; ++mf)
#pragma unroll
            for (int nf = 0; nf < 4; ++nf)
                acc[mf][nf] = __builtin_amdgcn_mfma_f32_16x16x32_bf16(
                    af[mf], bfr[nf], acc[mf][nf], 0, 0, 0);

        __syncthreads();   // protect LDS before next stage
    }

    // epilogue: C/D layout col = lane&15, row = (lane>>4)*4 + reg
    const int crow0 = brow + wr * 64;
    const int ccol0 = bcol + wc * 64;
#pragma unroll
    for (int mf = 0; mf < 4; ++mf)
#pragma unroll
        for (int nf = 0; nf < 4; ++nf)
#pragma unroll
            for (int r = 0; r < 4; ++r) {
                int row = crow0 + mf * 16 + kgrp * 4 + r;
                int col = ccol0 + nf * 16 + l15;
                C[(size_t)row * N + col] = acc[mf][nf][r];
            }
}

// --- fallback (only if ws too small): naive fp32, correct but slow ----------
__global__ void naive_kernel(const float* __restrict__ A, const float* __restrict__ W,
                             float* __restrict__ C, int M, int N, int K) {
    int col = blockIdx.x * blockDim.x + threadIdx.x;
    int row = blockIdx.y;
    if (col >= N || row >= M) return;
    float s = 0.0f;
    for (int k = 0; k < K; ++k) {
        float w = W[(size_t)k * N + col];
        float a = fabsf(w);
        if (a >= 0.5f && a < 1.5f) s += (w > 0.0f) ? A[(size_t)row * K + k] : -A[(size_t)row * K + k];
    }
    C[(size_t)row * N + col] = s;
}

extern "C" void kernel_launch(void* const* d_in, const int* in_sizes, int n_in,
                              void* d_out, int out_size, void* d_ws, size_t ws_size,
                              hipStream_t stream) {
    const float* A = (const float*)d_in[0];  // [M,K]
    const float* W = (const float*)d_in[1];  // [K,N]
    float* C = (float*)d_out;

    const int KN = in_sizes[1];              // K*N
    const int K = 4096, N = 4096;
    const int M = in_sizes[0] / K;           // 8192
    (void)KN;

    const size_t needA = (size_t)M * K * 2;
    const size_t needW = (size_t)N * K * 2;
    if (ws_size < needA + needW) {
        dim3 grid((N + 255) / 256, M);
        naive_kernel<<<grid, 256, 0, stream>>>(A, W, C, M, N, K);
        return;
    }

    unsigned short* Abf = (unsigned short*)d_ws;
    unsigned short* Wt = (unsigned short*)((char*)d_ws + needA);

    cvtA_kernel<<<2048, 256, 0, stream>>>(A, Abf, (long)M * K / 8);
    ternT_kernel<<<dim3(N / 64, K / 64), 256, 0, stream>>>(W, Wt, K, N);
    gemm_bf16_kernel<<<dim3(N / BN, M / BM), 256, 0, stream>>>(Abf, Wt, C, M, N, K);
}

// Round 2
// 263.536 us; speedup vs baseline: 1.5065x; 1.5065x over previous
//
#include <hip/hip_runtime.h>
#include <hip/hip_bf16.h>

// ---------------------------------------------------------------------------
// TernaryDense: C[M,N] = A[M,K] (fp32) @ ternary(W[K,N]) (fp32)
// Round 2: 256x256 8-phase GEMM (T1 XCD-swizzle, T2 LDS XOR-swizzle,
//          T3+T4 counted-vmcnt phase pipeline, T5 setprio).
// ---------------------------------------------------------------------------

#define LDSP(p) ((__attribute__((address_space(3))) void*)(p))
#define GLBP(p) ((const __attribute__((address_space(1))) void*)(p))

typedef __attribute__((ext_vector_type(8))) short bf16x8;
typedef __attribute__((ext_vector_type(4))) float f32x4;

static __device__ __forceinline__ unsigned short f2bf_rne(float f) {
    unsigned u = __float_as_uint(f);
    unsigned r = (u + 0x7FFFu + ((u >> 16) & 1u)) >> 16;
    return (unsigned short)r;
}

static __device__ __forceinline__ unsigned short tern_bf16(float v) {
    float a = fabsf(v);
    if (a >= 0.5f && a < 1.5f)
        return (v > 0.0f) ? (unsigned short)0x3F80u : (unsigned short)0xBF80u;
    return (unsigned short)0;
}

// --- pre-pass 1: A fp32 -> bf16 ---------------------------------------------
__global__ __launch_bounds__(256) void cvtA_kernel(
    const float* __restrict__ in, unsigned short* __restrict__ out, long n8) {
    long i = (long)blockIdx.x * blockDim.x + threadIdx.x;
    long stride = (long)gridDim.x * blockDim.x;
    for (; i < n8; i += stride) {
        float4 v0 = *(const float4*)(in + i * 8);
        float4 v1 = *(const float4*)(in + i * 8 + 4);
        unsigned short o[8] = {f2bf_rne(v0.x), f2bf_rne(v0.y), f2bf_rne(v0.z), f2bf_rne(v0.w),
                               f2bf_rne(v1.x), f2bf_rne(v1.y), f2bf_rne(v1.z), f2bf_rne(v1.w)};
        *(int4*)(out + i * 8) = *(const int4*)o;
    }
}

// --- pre-pass 2: ternarize W[K,N] and transpose -> Wt[N,K] bf16 -------------
__global__ __launch_bounds__(256) void ternT_kernel(
    const float* __restrict__ W, unsigned short* __restrict__ Wt, int K, int N) {
    __shared__ unsigned short tile[64][72];
    const int k0 = blockIdx.y * 64;
    const int n0 = blockIdx.x * 64;
    const int t = threadIdx.x;
#pragma unroll
    for (int i = 0; i < 4; ++i) {
        int e = i * 1024 + t * 4;
        int r = e >> 6, c = e & 63;
        float4 v = *(const float4*)(W + (size_t)(k0 + r) * N + n0 + c);
        tile[r][c + 0] = tern_bf16(v.x);
        tile[r][c + 1] = tern_bf16(v.y);
        tile[r][c + 2] = tern_bf16(v.z);
        tile[r][c + 3] = tern_bf16(v.w);
    }
    __syncthreads();
#pragma unroll
    for (int i = 0; i < 2; ++i) {
        int e = i * 2048 + t * 8;
        int n = e >> 6, kk = e & 63;
        unsigned short o[8];
#pragma unroll
        for (int j = 0; j < 8; ++j) o[j] = tile[kk + j][n];
        *(int4*)(Wt + (size_t)(n0 + n) * K + k0 + kk) = *(const int4*)o;
    }
}

// --- 8-phase 256^2 GEMM: C[M,N] = Abf[M,K] @ Bt[N,K]^T ----------------------
#define BM 256
#define BN 256
#define BK 64

#define FENCE() asm volatile("" ::: "memory")
#define BAR()                          \
    do {                               \
        FENCE();                       \
        __builtin_amdgcn_s_barrier();  \
        FENCE();                       \
    } while (0)

__global__ __launch_bounds__(512, 2) void gemm8p_kernel(
    const unsigned short* __restrict__ A,   // M x K bf16
    const unsigned short* __restrict__ Bt,  // N x K bf16
    float* __restrict__ C, int M, int N, int K) {
    // [buf][mat A=0/B=1][256 rows x 64 k], 32KB per tile, 128KB total
    __shared__ alignas(16) unsigned short lds[2][2][BM * BK];

    const int t = threadIdx.x;
    const int lane = t & 63;
    const int wave = t >> 6;
    const int wm = wave >> 2;   // 0..1
    const int wn = wave & 3;    // 0..3
    const int l15 = lane & 15;
    const int kgrp = lane >> 4; // 0..3

    // T1: bijective XCD swizzle (nwg % 8 == 0 here: 512)
    const int nbx = N / BN;
    const int nwg = nbx * (M / BM);
    const int qq = nwg >> 3;
    const int swz = ((int)blockIdx.x & 7) * qq + ((int)blockIdx.x >> 3);
    const int brow = (swz / nbx) * BM;
    const int bcol = (swz % nbx) * BN;

    const int NKT = K / BK;
    const int NIT = NKT / 2;

    // stage one 16KB half (mat: 0=A,1=B; h: 0/1) of K-tile kt into buffer b.
    // LDS dest linear; inverse T2 swizzle applied to the GLOBAL source addr.
    auto stage_half = [&](int b, int mat, int h, int kt) {
        const unsigned short* sb = mat ? Bt : A;
        const int rowbase = mat ? bcol : brow;
#pragma unroll
        for (int iss = 0; iss < 2; ++iss) {
            int Lb = h * 16384 + iss * 8192 + t * 16;  // byte in 32KB tile
            int row = Lb >> 7;                          // tile row 0..255
            int kb = (Lb & 127) ^ ((row & 7) << 4);     // swizzled k-byte
            const char* src = (const char*)sb +
                ((size_t)(rowbase + row) * K + (size_t)kt * BK) * 2 + kb;
            unsigned short* dst =
                &lds[b][mat][0] + (h * 16384 + iss * 8192 + wave * 1024) / 2;
            __builtin_amdgcn_global_load_lds(GLBP(src), LDSP(dst), 16, 0, 0);
        }
    };

    auto read_A = [&](int b, int mf, int ks) -> bf16x8 {
        int row = wm * 128 + mf * 16 + l15;
        int kb = (kgrp * 16 + ks * 64) ^ ((row & 7) << 4);
        return *(const bf16x8*)((const char*)&lds[b][0][0] + row * 128 + kb);
    };
    auto read_B = [&](int b, int nf, int ks) -> bf16x8 {
        int row = wn * 64 + nf * 16 + l15;
        int kb = (kgrp * 16 + ks * 64) ^ ((row & 7) << 4);
        return *(const bf16x8*)((const char*)&lds[b][1][0] + row * 128 + kb);
    };

    f32x4 acc[8][4] = {};
    bf16x8 af[4][2], bfr[4][2];

    // prologue: buf0 fully (kt0), buf1.B halves (kt1); wait buf0 only
    stage_half(0, 1, 0, 0);
    stage_half(0, 1, 1, 0);
    stage_half(0, 0, 0, 0);
    stage_half(0, 0, 1, 0);
    stage_half(1, 1, 0, 1);
    stage_half(1, 1, 1, 1);
    asm volatile("s_waitcnt vmcnt(4)" ::: "memory");
    BAR();

    for (int it = 0; it < NIT; ++it) {
        const int kA = 2 * it + 1;           // buf1.A fill (consumed this iter)
        const int kB0 = (2 * it + 2) % NKT;  // buf0 next K-tile
        const int kB1 = (2 * it + 3) % NKT;  // buf1 next K-tile

#define PHASE_MFMA(MB, NB)                                                     \
        __builtin_amdgcn_s_setprio(1);                                         \
        _Pragma("unroll") for (int mf = 0; mf < 4; ++mf)                       \
            _Pragma("unroll") for (int nf = 0; nf < 2; ++nf)                   \
                _Pragma("unroll") for (int ks = 0; ks < 2; ++ks)               \
                    acc[(MB) + mf][(NB) + nf] =                                \
                        __builtin_amdgcn_mfma_f32_16x16x32_bf16(               \
                            af[mf][ks], bfr[(NB) + nf][ks],                    \
                            acc[(MB) + mf][(NB) + nf], 0, 0, 0);               \
        __builtin_amdgcn_s_setprio(0);

        // ---- phase 1: (m0-3 x n0-1) from buf0
#pragma unroll
        for (int mf = 0; mf < 4; ++mf) { af[mf][0] = read_A(0, mf, 0); af[mf][1] = read_A(0, mf, 1); }
#pragma unroll
        for (int nf = 0; nf < 2; ++nf) { bfr[nf][0] = read_B(0, nf, 0); bfr[nf][1] = read_B(0, nf, 1); }
        stage_half(1, 0, 0, kA);
        BAR();
        PHASE_MFMA(0, 0)
        BAR();
        // ---- phase 2: (m0-3 x n2-3)
#pragma unroll
        for (int nf = 2; nf < 4; ++nf) { bfr[nf][0] = read_B(0, nf, 0); bfr[nf][1] = read_B(0, nf, 1); }
        stage_half(1, 0, 1, kA);
        BAR();
        PHASE_MFMA(0, 2)
        BAR();
        // ---- phase 3: (m4-7 x n0-1)
#pragma unroll
        for (int mf = 0; mf < 4; ++mf) { af[mf][0] = read_A(0, mf + 4, 0); af[mf][1] = read_A(0, mf + 4, 1); }
        stage_half(0, 1, 0, kB0);
        BAR();
        PHASE_MFMA(4, 0)
        BAR();
        // ---- phase 4: (m4-7 x n2-3), counted vmcnt
        stage_half(0, 1, 1, kB0);
        BAR();
        PHASE_MFMA(4, 2)
        asm volatile("s_waitcnt vmcnt(4)" ::: "memory");
        BAR();
        // ---- phase 5: (m0-3 x n0-1) from buf1
#pragma unroll
        for (int mf = 0; mf < 4; ++mf) { af[mf][0] = read_A(1, mf, 0); af[mf][1] = read_A(1, mf, 1); }
#pragma unroll
        for (int nf = 0; nf < 2; ++nf) { bfr[nf][0] = read_B(1, nf, 0); bfr[nf][1] = read_B(1, nf, 1); }
        stage_half(0, 0, 0, kB0);
        BAR();
        PHASE_MFMA(0, 0)
        BAR();
        // ---- phase 6: (m0-3 x n2-3)
#pragma unroll
        for (int nf = 2; nf < 4; ++nf) { bfr[nf][0] = read_B(1, nf, 0); bfr[nf][1] = read_B(1, nf, 1); }
        stage_half(0, 0, 1, kB0);
        BAR();
        PHASE_MFMA(0, 2)
        BAR();
        // ---- phase 7: (m4-7 x n0-1)
#pragma unroll
        for (int mf = 0; mf < 4; ++mf) { af[mf][0] = read_A(1, mf + 4, 0); af[mf][1] = read_A(1, mf + 4, 1); }
        stage_half(1, 1, 0, kB1);
        BAR();
        PHASE_MFMA(4, 0)
        BAR();
        // ---- phase 8: (m4-7 x n2-3), counted vmcnt
        stage_half(1, 1, 1, kB1);
        BAR();
        PHASE_MFMA(4, 2)
        asm volatile("s_waitcnt vmcnt(4)" ::: "memory");
        BAR();
#undef PHASE_MFMA
    }

    // epilogue: C/D layout col = lane&15, row = (lane>>4)*4 + reg
    const int crow0 = brow + wm * 128;
    const int ccol0 = bcol + wn * 64;
#pragma unroll
    for (int mf = 0; mf < 8; ++mf)
#pragma unroll
        for (int nf = 0; nf < 4; ++nf)
#pragma unroll
            for (int r = 0; r < 4; ++r) {
                int row = crow0 + mf * 16 + kgrp * 4 + r;
                int col = ccol0 + nf * 16 + l15;
                C[(size_t)row * N + col] = acc[mf][nf][r];
            }
}

// --- fallback: naive fp32 (never expected to trigger) -----------------------
__global__ void naive_kernel(const float* __restrict__ A, const float* __restrict__ W,
                             float* __restrict__ C, int M, int N, int K) {
    int col = blockIdx.x * blockDim.x + threadIdx.x;
    int row = blockIdx.y;
    if (col >= N || row >= M) return;
    float s = 0.0f;
    for (int k = 0; k < K; ++k) {
        float w = W[(size_t)k * N + col];
        float a = fabsf(w);
        if (a >= 0.5f && a < 1.5f) s += (w > 0.0f) ? A[(size_t)row * K + k] : -A[(size_t)row * K + k];
    }
    C[(size_t)row * N + col] = s;
}

extern "C" void kernel_launch(void* const* d_in, const int* in_sizes, int n_in,
                              void* d_out, int out_size, void* d_ws, size_t ws_size,
                              hipStream_t stream) {
    const float* A = (const float*)d_in[0];  // [M,K]
    const float* W = (const float*)d_in[1];  // [K,N]
    float* C = (float*)d_out;

    const int K = 4096, N = 4096;
    const int M = in_sizes[0] / K;  // 8192

    const size_t needA = (size_t)M * K * 2;
    const size_t needW = (size_t)N * K * 2;
    const bool divisible = (M % BM == 0) && (N % BN == 0) && (K % (2 * BK) == 0);
    if (ws_size < needA + needW || !divisible) {
        dim3 grid((N + 255) / 256, M);
        naive_kernel<<<grid, 256, 0, stream>>>(A, W, C, M, N, K);
        return;
    }

    unsigned short* Abf = (unsigned short*)d_ws;
    unsigned short* Wt = (unsigned short*)((char*)d_ws + needA);

    cvtA_kernel<<<2048, 256, 0, stream>>>(A, Abf, (long)M * K / 8);
    ternT_kernel<<<dim3(N / 64, K / 64), 256, 0, stream>>>(W, Wt, K, N);

    const int nwg = (M / BM) * (N / BN);  // 512
    gemm8p_kernel<<<dim3(nwg), 512, 0, stream>>>(Abf, Wt, C, M, N, K);
}